// Round 6
// baseline (430.309 us; speedup 1.0000x reference)
//
#include <hip/hip_runtime.h>
#include <cmath>

typedef __attribute__((ext_vector_type(8))) short bf16x8;
typedef __attribute__((ext_vector_type(4))) short bf16x4;
typedef __attribute__((ext_vector_type(4))) float f32x4;

__device__ __forceinline__ float bf2f(ushort u) {
    union { unsigned int u; float f; } c;
    c.u = ((unsigned int)u) << 16;
    return c.f;
}
__device__ __forceinline__ ushort f2bf(float f) {
    union { float f; unsigned int u; } c;
    c.f = f;
    unsigned int lsb = (c.u >> 16) & 1u;
    return (ushort)((c.u + 0x7fffu + lsb) >> 16);
}

// 8-bf16 LDS load from an 8B-aligned address
__device__ __forceinline__ bf16x8 lds_ld8(const ushort* p) {
    const bf16x4 lo = *(const bf16x4*)p;
    const bf16x4 hi = *(const bf16x4*)(p + 4);
    bf16x8 r;
    r[0] = lo[0]; r[1] = lo[1]; r[2] = lo[2]; r[3] = lo[3];
    r[4] = hi[0]; r[5] = hi[1]; r[6] = hi[2]; r[7] = hi[3];
    return r;
}

// async global->LDS, 16B per lane. LDS dest = wave-uniform base + lane*16.
__device__ __forceinline__ void gl2lds16(const ushort* g, ushort* l) {
    __builtin_amdgcn_global_load_lds((const __attribute__((address_space(1))) void*)g,
                                     (__attribute__((address_space(3))) void*)l,
                                     16, 0, 0);
}

// ---------------------------------------------------------------------------
__global__ __launch_bounds__(256) void cast_bf16(const float* __restrict__ in,
                                                 ushort* __restrict__ out, int n)
{
    int i = (blockIdx.x * 256 + threadIdx.x) * 4;
    if (i < n) {
        const float4 v = *(const float4*)(in + i);
        ushort4 o;
        o.x = f2bf(v.x); o.y = f2bf(v.y); o.z = f2bf(v.z); o.w = f2bf(v.w);
        *(ushort4*)(out + i) = o;
    }
}

// transpose + cast: in (R,C) fp32 row-major -> out (C,R) bf16 row-major
__global__ __launch_bounds__(256) void transpose_cast(const float* __restrict__ in,
                                                      ushort* __restrict__ out,
                                                      int R, int C)
{
    __shared__ float t[32][33];
    const int tx = threadIdx.x & 31;
    const int ty = threadIdx.x >> 5;
    const int r0 = blockIdx.y << 5;
    const int c0 = blockIdx.x << 5;
    #pragma unroll
    for (int i = ty; i < 32; i += 8)
        t[i][tx] = in[(size_t)(r0 + i) * C + c0 + tx];
    __syncthreads();
    #pragma unroll
    for (int i = ty; i < 32; i += 8)
        out[(size_t)(c0 + i) * R + r0 + tx] = f2bf(t[tx][i]);
}

// b_cat[n] = sum_o bq[o]*wuk[n][o] for n<512, else 0   (fp32, n in 0..1023)
__global__ __launch_bounds__(256) void bias_fold(const float* __restrict__ bq,
                                                 const float* __restrict__ wuk,
                                                 float* __restrict__ b_cat)
{
    const int n = blockIdx.x * 256 + threadIdx.x;
    float s = 0.f;
    if (n < 512) {
        for (int o = 0; o < 1024; o += 4) {
            const float4 w = *(const float4*)(wuk + (size_t)n * 1024 + o);
            const float4 q = *(const float4*)(bq + o);
            s = fmaf(q.x, w.x, s); s = fmaf(q.y, w.y, s);
            s = fmaf(q.z, w.z, s); s = fmaf(q.w, w.w, s);
        }
    }
    b_cat[n] = s;
}

// mkmin[b] = min_s mask[b, s]   (one block per batch)
__global__ __launch_bounds__(256) void mask_min(const float* __restrict__ mask,
                                                float* __restrict__ mkmin)
{
    __shared__ float red[4];
    const int b = blockIdx.x;
    const int tid = threadIdx.x;
    const float4 v = *(const float4*)(mask + b * 1024 + tid * 4);
    float m = fminf(fminf(v.x, v.y), fminf(v.z, v.w));
    #pragma unroll
    for (int off = 32; off >= 1; off >>= 1)
        m = fminf(m, __shfl_xor(m, off));
    if ((tid & 63) == 0) red[tid >> 6] = m;
    __syncthreads();
    if (tid == 0)
        mkmin[b] = fminf(fminf(red[0], red[1]), fminf(red[2], red[3]));
}

// ---------------------------------------------------------------------------
// bf16 MFMA GEMM: C[M,N] = A[M,K] @ Bt[N,K]^T (+bias), strided rows.
// 128x128x32 tile, 256 threads = 4 waves (2x2), each wave 4x4 of 16x16x32.
// ---------------------------------------------------------------------------
template<bool OUT_F32, bool HAS_BIAS>
__global__ __launch_bounds__(256) void gemm_bt(const ushort* __restrict__ A,
                                               const ushort* __restrict__ Bt,
                                               const float* __restrict__ bias,
                                               void* __restrict__ Cv,
                                               int M, int N, int K,
                                               int lda, int ldb, int ldc)
{
    __shared__ ushort As[128 * 32];
    __shared__ ushort Bs[128 * 32];

    const int tid  = threadIdx.x;
    const int wave = tid >> 6;
    const int lane = tid & 63;
    const int row0 = blockIdx.y << 7;
    const int col0 = blockIdx.x << 7;

    const int srow = lane >> 2;
    const int skc  = (lane & 3) << 3;
    const ushort* Ag0 = A  + (size_t)(row0 + wave * 32 +      srow) * lda + skc;
    const ushort* Ag1 = A  + (size_t)(row0 + wave * 32 + 16 + srow) * lda + skc;
    const ushort* Bg0 = Bt + (size_t)(col0 + wave * 32 +      srow) * ldb + skc;
    const ushort* Bg1 = Bt + (size_t)(col0 + wave * 32 + 16 + srow) * ldb + skc;
    ushort* Asl0 = &As[(wave * 2 + 0) * 512];
    ushort* Asl1 = &As[(wave * 2 + 1) * 512];
    ushort* Bsl0 = &Bs[(wave * 2 + 0) * 512];
    ushort* Bsl1 = &Bs[(wave * 2 + 1) * 512];

    const int wr = (wave >> 1) << 6;
    const int wc = (wave & 1) << 6;
    const int ln = lane & 15;
    const int hi = lane >> 4;
    const int a_off = (wr + ln) * 32 + hi * 8;
    const int b_off = (wc + ln) * 32 + hi * 8;

    f32x4 acc[4][4];
    #pragma unroll
    for (int i = 0; i < 4; ++i)
        #pragma unroll
        for (int j = 0; j < 4; ++j)
            acc[i][j] = (f32x4){0.f, 0.f, 0.f, 0.f};

    for (int k0 = 0; k0 < K; k0 += 32) {
        __syncthreads();
        gl2lds16(Ag0 + k0, Asl0);
        gl2lds16(Ag1 + k0, Asl1);
        gl2lds16(Bg0 + k0, Bsl0);
        gl2lds16(Bg1 + k0, Bsl1);
        __syncthreads();

        bf16x8 a[4], b[4];
        #pragma unroll
        for (int i = 0; i < 4; ++i) a[i] = *(const bf16x8*)&As[a_off + i * 512];
        #pragma unroll
        for (int j = 0; j < 4; ++j) b[j] = *(const bf16x8*)&Bs[b_off + j * 512];
        #pragma unroll
        for (int i = 0; i < 4; ++i)
            #pragma unroll
            for (int j = 0; j < 4; ++j)
                acc[i][j] = __builtin_amdgcn_mfma_f32_16x16x32_bf16(a[i], b[j], acc[i][j], 0, 0, 0);
    }

    #pragma unroll
    for (int j = 0; j < 4; ++j) {
        const int col = col0 + wc + (j << 4) + ln;
        const float bb = HAS_BIAS ? bias[col] : 0.f;
        #pragma unroll
        for (int i = 0; i < 4; ++i) {
            const int rbase = row0 + wr + (i << 4) + (hi << 2);
            #pragma unroll
            for (int r = 0; r < 4; ++r) {
                const float v = acc[i][j][r] + bb;
                if (OUT_F32) ((float*)Cv)[(size_t)(rbase + r) * ldc + col] = v;
                else         ((ushort*)Cv)[(size_t)(rbase + r) * ldc + col] = f2bf(v);
            }
        }
    }
}

// ---------------------------------------------------------------------------
// MFMA flash attention, no online softmax. Block = (b, h, 64q); 4 waves x 16q.
//   qc: fused (8192, 1024) bf16 — cols [0,512) = q_latent, [512,1024) = K
//   vT: (1024, 8192) bf16 — row (h*64+c), col (b*1024+s)
// t_rowmax = -1e9*min(1, fl(m_q + mk_min_b)) == max_j t_j exactly (fp32 ops
// monotone), and |s*scale| <= ~3, so p = exp(v - t_rowmax) never overflows and
// normalization cancels the shift. No running max / alpha rescale / per-tile
// shuffles; per-lane l partial sums, one 4-shuffle reduction at the end.
// K and V register-prefetched one full tile ahead.
// Mask arithmetic exact fp32 (__fadd_rn/__fmul_rn) as in rounds 2-5.
// ---------------------------------------------------------------------------
__global__ __launch_bounds__(256) void attn_mfma(const ushort* __restrict__ qc,
                                                 const ushort* __restrict__ vT,
                                                 const float* __restrict__ mask,
                                                 const float* __restrict__ mkmin,
                                                 ushort* __restrict__ z)
{
    __shared__ ushort Ps[4][16][68];     // per-wave P: [wave][q][key]
    __shared__ float  mk_s[1024];        // full key-mask row for batch b

    const int tid  = threadIdx.x;
    const int wave = tid >> 6;
    const int lane = tid & 63;
    const int ln   = lane & 15;
    const int hi   = lane >> 4;
    const int qt = blockIdx.x, h = blockIdx.y, b = blockIdx.z;
    const int s0q = qt << 6;

    // stage the key-mask row once (4 KB), single barrier
    *(float4*)&mk_s[tid << 2] = *(const float4*)(mask + b * 1024 + (tid << 2));
    __syncthreads();

    // Q A-frag: query = s0q+16*wave+ln, dims hi*8..+7 (one frag covers d=32)
    const bf16x8 aq = *(const bf16x8*)(qc + (size_t)(b * 1024 + s0q + wave * 16 + ln) * 1024 + h * 32 + hi * 8);

    const float mk_min = mkmin[b];
    float mqv[4], t_max[4];
    #pragma unroll
    for (int r = 0; r < 4; ++r) {
        mqv[r] = mask[b * 1024 + s0q + wave * 16 + hi * 4 + r];
        t_max[r] = __fmul_rn(fminf(1.f, __fadd_rn(mqv[r], mk_min)), -1.0e9f);
    }

    // K/V fragment base pointers (at s0k = 0)
    const ushort* kp[4];
    const ushort* vp[4];
    #pragma unroll
    for (int j = 0; j < 4; ++j) {
        kp[j] = qc + 512 + (size_t)(b * 1024 + j * 16 + ln) * 1024 + h * 32 + hi * 8;
        vp[j] = vT + (size_t)(h * 64 + j * 16 + ln) * 8192 + b * 1024 + hi * 8;
    }

    // preload tile 0
    bf16x8 kcur[4], vcur0[4], vcur1[4];
    #pragma unroll
    for (int j = 0; j < 4; ++j) {
        kcur[j]  = *(const bf16x8*)kp[j];
        vcur0[j] = *(const bf16x8*)vp[j];
        vcur1[j] = *(const bf16x8*)(vp[j] + 32);
    }

    f32x4 acc_o[4];
    #pragma unroll
    for (int jo = 0; jo < 4; ++jo) acc_o[jo] = (f32x4){0.f, 0.f, 0.f, 0.f};
    float l_run[4] = {0.f, 0.f, 0.f, 0.f};

    const float scale = 0.17677669529663687f;   // 1/sqrt(32)

    for (int kt = 0; kt < 16; ++kt) {
        // QK MFMAs on current K fragments (registers, loaded last iteration)
        f32x4 accS[4];
        #pragma unroll
        for (int j = 0; j < 4; ++j)
            accS[j] = __builtin_amdgcn_mfma_f32_16x16x32_bf16(aq, kcur[j], (f32x4){0.f, 0.f, 0.f, 0.f}, 0, 0, 0);

        // prefetch tile kt+1 (K and both V halves) — consumed next iteration
        bf16x8 knext[4], vnext0[4], vnext1[4];
        const int noff = ((kt + 1) & 15) << 6;
        #pragma unroll
        for (int j = 0; j < 4; ++j) {
            knext[j]  = *(const bf16x8*)(kp[j] + (size_t)noff * 1024);
            vnext0[j] = *(const bf16x8*)(vp[j] + noff);
            vnext1[j] = *(const bf16x8*)(vp[j] + noff + 32);
        }

        // key mask from LDS
        float mkv[4];
        #pragma unroll
        for (int j = 0; j < 4; ++j) mkv[j] = mk_s[(kt << 6) + j * 16 + ln];

        // softmax numerators, no cross-lane ops (row = hi*4+r, col = j*16+ln)
        #pragma unroll
        for (int r = 0; r < 4; ++r) {
            #pragma unroll
            for (int j = 0; j < 4; ++j) {
                const float m2 = fminf(1.f, __fadd_rn(mqv[r], mkv[j]));
                const float t  = __fmul_rn(m2, -1.0e9f);
                const float v  = __fadd_rn(__fmul_rn(accS[j][r], scale), t);
                const float p  = __expf(v - t_max[r]);
                l_run[r] += p;
                Ps[wave][hi * 4 + r][j * 16 + ln] = f2bf(p);
            }
        }

        // P: C-layout -> per-wave LDS -> A-frags (wave-local, no barrier)
        const bf16x8 pa0 = lds_ld8(&Ps[wave][ln][hi * 8]);
        const bf16x8 pa1 = lds_ld8(&Ps[wave][ln][32 + hi * 8]);

        // PV MFMAs with V fragments loaded one iteration ago
        #pragma unroll
        for (int jo = 0; jo < 4; ++jo) {
            acc_o[jo] = __builtin_amdgcn_mfma_f32_16x16x32_bf16(pa0, vcur0[jo], acc_o[jo], 0, 0, 0);
            acc_o[jo] = __builtin_amdgcn_mfma_f32_16x16x32_bf16(pa1, vcur1[jo], acc_o[jo], 0, 0, 0);
        }

        #pragma unroll
        for (int j = 0; j < 4; ++j) {
            kcur[j]  = knext[j];
            vcur0[j] = vnext0[j];
            vcur1[j] = vnext1[j];
        }
    }

    // final l reduction across the 16 lanes of each row (once per kernel)
    #pragma unroll
    for (int r = 0; r < 4; ++r) {
        #pragma unroll
        for (int off = 8; off >= 1; off >>= 1)
            l_run[r] += __shfl_xor(l_run[r], off);
    }

    float invl[4];
    #pragma unroll
    for (int r = 0; r < 4; ++r) invl[r] = 1.f / l_run[r];
    #pragma unroll
    for (int jo = 0; jo < 4; ++jo)
        #pragma unroll
        for (int r = 0; r < 4; ++r)
            z[(size_t)(b * 1024 + s0q + wave * 16 + hi * 4 + r) * 1024 + h * 64 + jo * 16 + ln]
                = f2bf(acc_o[jo][r] * invl[r]);
}

// ---------------------------------------------------------------------------
extern "C" void kernel_launch(void* const* d_in, const int* in_sizes, int n_in,
                              void* d_out, int out_size, void* d_ws, size_t ws_size,
                              hipStream_t stream)
{
    const float* x     = (const float*)d_in[0];
    const float* mask  = (const float*)d_in[1];
    const float* wq    = (const float*)d_in[2];
    const float* bq    = (const float*)d_in[3];
    const float* w_ckv = (const float*)d_in[4];
    const float* wuk   = (const float*)d_in[5];
    const float* wuv   = (const float*)d_in[6];
    const float* wo    = (const float*)d_in[7];
    const float* bo    = (const float*)d_in[8];
    float* out = (float*)d_out;

    char* ws = (char*)d_ws;
    ushort* x_bf   = (ushort*)(ws);                         // 16 MB
    ushort* qc     = (ushort*)(ws + (size_t)(16u << 20));   // 16 MB (q_latent|K)
    ushort* vT     = (ushort*)(ws + (size_t)(32u << 20));   // 16 MB (1024,8192)
    ushort* z      = (ushort*)(ws + (size_t)(48u << 20));   // 16 MB
    ushort* wq_bf  = (ushort*)(ws + (size_t)(64u << 20));   //  2 MB
    ushort* wuk_bf = (ushort*)(ws + (size_t)(66u << 20));   //  1 MB
    ushort* wuv_t  = (ushort*)(ws + (size_t)(67u << 20));   //  1 MB
    ushort* wo_t   = (ushort*)(ws + (size_t)(68u << 20));   //  2 MB
    ushort* wcat_t = (ushort*)(ws + (size_t)(70u << 20));   //  2 MB (1024,1024)
    float*  b_cat  = (float*) (ws + (size_t)(72u << 20));   //  4 KB
    float*  mkmin  = (float*) (ws + (size_t)(72u << 20) + 8192); // 32 B

    const dim3 blk(256);
    const int M = 8192;

    cast_bf16<<<dim3(8192), blk, 0, stream>>>(x,   x_bf,   8192 * 1024);
    cast_bf16<<<dim3(1024), blk, 0, stream>>>(wq,  wq_bf,  1024 * 1024);
    cast_bf16<<<dim3(512),  blk, 0, stream>>>(wuk, wuk_bf, 512 * 1024);
    // wcat rows 512..1023 = w_ckv^T
    transpose_cast<<<dim3(16, 32), blk, 0, stream>>>(w_ckv, wcat_t + (size_t)512 * 1024, 1024, 512);
    transpose_cast<<<dim3(32, 16), blk, 0, stream>>>(wuv,   wuv_t,  512,  1024);
    transpose_cast<<<dim3(32, 32), blk, 0, stream>>>(wo,    wo_t,   1024, 1024);
    bias_fold<<<dim3(4), blk, 0, stream>>>(bq, wuk, b_cat);
    mask_min<<<dim3(8), blk, 0, stream>>>(mask, mkmin);

    // wcat rows 0..511 = wqk[l][d] = sum_n wuk[l][n]*wq[d][n]
    gemm_bt<false, false><<<dim3(8, 4), blk, 0, stream>>>(wuk_bf, wq_bf, nullptr, wcat_t,
                                                          512, 1024, 1024, 1024, 1024, 1024);

    // qc = x @ wcat^T + b_cat     (8192, 1024, K=1024): [q_latent | combined]
    gemm_bt<false, true ><<<dim3(8, 64), blk, 0, stream>>>(x_bf, wcat_t, b_cat, qc,
                                                           M, 1024, 1024, 1024, 1024, 1024);

    // vT = wuv^T @ combined^T     (1024, 8192, K=512)
    gemm_bt<false, false><<<dim3(64, 8), blk, 0, stream>>>(wuv_t, qc + 512, nullptr, vT,
                                                           1024, M, 512, 512, 1024, 8192);

    attn_mfma<<<dim3(16, 16, 8), blk, 0, stream>>>(qc, vT, mask, mkmin, z);

    // out = z @ wo^T + bo         (8192, 1024, K=1024)
    gemm_bt<true,  true ><<<dim3(8, 64), blk, 0, stream>>>(z, wo_t, bo, out,
                                                           M, 1024, 1024, 1024, 1024, 1024);
}

// Round 7
// 319.542 us; speedup vs baseline: 1.3466x; 1.3466x over previous
//
#include <hip/hip_runtime.h>
#include <cmath>

typedef __attribute__((ext_vector_type(8))) short bf16x8;
typedef __attribute__((ext_vector_type(4))) short bf16x4;
typedef __attribute__((ext_vector_type(4))) float f32x4;

__device__ __forceinline__ float bf2f(ushort u) {
    union { unsigned int u; float f; } c;
    c.u = ((unsigned int)u) << 16;
    return c.f;
}
__device__ __forceinline__ ushort f2bf(float f) {
    union { float f; unsigned int u; } c;
    c.f = f;
    unsigned int lsb = (c.u >> 16) & 1u;
    return (ushort)((c.u + 0x7fffu + lsb) >> 16);
}

// 8-bf16 LDS load from an 8B-aligned address
__device__ __forceinline__ bf16x8 lds_ld8(const ushort* p) {
    const bf16x4 lo = *(const bf16x4*)p;
    const bf16x4 hi = *(const bf16x4*)(p + 4);
    bf16x8 r;
    r[0] = lo[0]; r[1] = lo[1]; r[2] = lo[2]; r[3] = lo[3];
    r[4] = hi[0]; r[5] = hi[1]; r[6] = hi[2]; r[7] = hi[3];
    return r;
}

// async global->LDS, 16B per lane. LDS dest = wave-uniform base + lane*16.
__device__ __forceinline__ void gl2lds16(const ushort* g, ushort* l) {
    __builtin_amdgcn_global_load_lds((const __attribute__((address_space(1))) void*)g,
                                     (__attribute__((address_space(3))) void*)l,
                                     16, 0, 0);
}

// ---------------------------------------------------------------------------
__global__ __launch_bounds__(256) void cast_bf16(const float* __restrict__ in,
                                                 ushort* __restrict__ out, int n)
{
    int i = (blockIdx.x * 256 + threadIdx.x) * 4;
    if (i < n) {
        const float4 v = *(const float4*)(in + i);
        ushort4 o;
        o.x = f2bf(v.x); o.y = f2bf(v.y); o.z = f2bf(v.z); o.w = f2bf(v.w);
        *(ushort4*)(out + i) = o;
    }
}

// transpose + cast: in (R,C) fp32 row-major -> out (C,R) bf16 row-major
__global__ __launch_bounds__(256) void transpose_cast(const float* __restrict__ in,
                                                      ushort* __restrict__ out,
                                                      int R, int C)
{
    __shared__ float t[32][33];
    const int tx = threadIdx.x & 31;
    const int ty = threadIdx.x >> 5;
    const int r0 = blockIdx.y << 5;
    const int c0 = blockIdx.x << 5;
    #pragma unroll
    for (int i = ty; i < 32; i += 8)
        t[i][tx] = in[(size_t)(r0 + i) * C + c0 + tx];
    __syncthreads();
    #pragma unroll
    for (int i = ty; i < 32; i += 8)
        out[(size_t)(c0 + i) * R + r0 + tx] = f2bf(t[tx][i]);
}

// b_cat[n] = sum_o bq[o]*wuk[n][o] for n<512, else 0   (fp32, n in 0..1023)
__global__ __launch_bounds__(256) void bias_fold(const float* __restrict__ bq,
                                                 const float* __restrict__ wuk,
                                                 float* __restrict__ b_cat)
{
    const int n = blockIdx.x * 256 + threadIdx.x;
    float s = 0.f;
    if (n < 512) {
        for (int o = 0; o < 1024; o += 4) {
            const float4 w = *(const float4*)(wuk + (size_t)n * 1024 + o);
            const float4 q = *(const float4*)(bq + o);
            s = fmaf(q.x, w.x, s); s = fmaf(q.y, w.y, s);
            s = fmaf(q.z, w.z, s); s = fmaf(q.w, w.w, s);
        }
    }
    b_cat[n] = s;
}

// mkmin[b] = min_s mask[b, s]   (one block per batch)
__global__ __launch_bounds__(256) void mask_min(const float* __restrict__ mask,
                                                float* __restrict__ mkmin)
{
    __shared__ float red[4];
    const int b = blockIdx.x;
    const int tid = threadIdx.x;
    const float4 v = *(const float4*)(mask + b * 1024 + tid * 4);
    float m = fminf(fminf(v.x, v.y), fminf(v.z, v.w));
    #pragma unroll
    for (int off = 32; off >= 1; off >>= 1)
        m = fminf(m, __shfl_xor(m, off));
    if ((tid & 63) == 0) red[tid >> 6] = m;
    __syncthreads();
    if (tid == 0)
        mkmin[b] = fminf(fminf(red[0], red[1]), fminf(red[2], red[3]));
}

// ---------------------------------------------------------------------------
// bf16 MFMA GEMM: C[M,N] = A[M,K] @ Bt[N,K]^T (+bias), strided rows.
// 128x128x32 tile, 256 threads = 4 waves (2x2), each wave 4x4 of 16x16x32.
// ---------------------------------------------------------------------------
template<bool OUT_F32, bool HAS_BIAS>
__global__ __launch_bounds__(256) void gemm_bt(const ushort* __restrict__ A,
                                               const ushort* __restrict__ Bt,
                                               const float* __restrict__ bias,
                                               void* __restrict__ Cv,
                                               int M, int N, int K,
                                               int lda, int ldb, int ldc)
{
    __shared__ ushort As[128 * 32];
    __shared__ ushort Bs[128 * 32];

    const int tid  = threadIdx.x;
    const int wave = tid >> 6;
    const int lane = tid & 63;
    const int row0 = blockIdx.y << 7;
    const int col0 = blockIdx.x << 7;

    const int srow = lane >> 2;
    const int skc  = (lane & 3) << 3;
    const ushort* Ag0 = A  + (size_t)(row0 + wave * 32 +      srow) * lda + skc;
    const ushort* Ag1 = A  + (size_t)(row0 + wave * 32 + 16 + srow) * lda + skc;
    const ushort* Bg0 = Bt + (size_t)(col0 + wave * 32 +      srow) * ldb + skc;
    const ushort* Bg1 = Bt + (size_t)(col0 + wave * 32 + 16 + srow) * ldb + skc;
    ushort* Asl0 = &As[(wave * 2 + 0) * 512];
    ushort* Asl1 = &As[(wave * 2 + 1) * 512];
    ushort* Bsl0 = &Bs[(wave * 2 + 0) * 512];
    ushort* Bsl1 = &Bs[(wave * 2 + 1) * 512];

    const int wr = (wave >> 1) << 6;
    const int wc = (wave & 1) << 6;
    const int ln = lane & 15;
    const int hi = lane >> 4;
    const int a_off = (wr + ln) * 32 + hi * 8;
    const int b_off = (wc + ln) * 32 + hi * 8;

    f32x4 acc[4][4];
    #pragma unroll
    for (int i = 0; i < 4; ++i)
        #pragma unroll
        for (int j = 0; j < 4; ++j)
            acc[i][j] = (f32x4){0.f, 0.f, 0.f, 0.f};

    for (int k0 = 0; k0 < K; k0 += 32) {
        __syncthreads();
        gl2lds16(Ag0 + k0, Asl0);
        gl2lds16(Ag1 + k0, Asl1);
        gl2lds16(Bg0 + k0, Bsl0);
        gl2lds16(Bg1 + k0, Bsl1);
        __syncthreads();

        bf16x8 a[4], b[4];
        #pragma unroll
        for (int i = 0; i < 4; ++i) a[i] = *(const bf16x8*)&As[a_off + i * 512];
        #pragma unroll
        for (int j = 0; j < 4; ++j) b[j] = *(const bf16x8*)&Bs[b_off + j * 512];
        #pragma unroll
        for (int i = 0; i < 4; ++i)
            #pragma unroll
            for (int j = 0; j < 4; ++j)
                acc[i][j] = __builtin_amdgcn_mfma_f32_16x16x32_bf16(a[i], b[j], acc[i][j], 0, 0, 0);
    }

    #pragma unroll
    for (int j = 0; j < 4; ++j) {
        const int col = col0 + wc + (j << 4) + ln;
        const float bb = HAS_BIAS ? bias[col] : 0.f;
        #pragma unroll
        for (int i = 0; i < 4; ++i) {
            const int rbase = row0 + wr + (i << 4) + (hi << 2);
            #pragma unroll
            for (int r = 0; r < 4; ++r) {
                const float v = acc[i][j][r] + bb;
                if (OUT_F32) ((float*)Cv)[(size_t)(rbase + r) * ldc + col] = v;
                else         ((ushort*)Cv)[(size_t)(rbase + r) * ldc + col] = f2bf(v);
            }
        }
    }
}

// ---------------------------------------------------------------------------
// MFMA flash attention, gemm_bt-style cooperative LDS staging.
// Block = (b, h, 128-query tile); 4 waves x 32 queries. Grid 1024 = 4 blk/CU.
//   qc: fused (8192, 1024) bf16 — cols [0,512) = q_latent, [512,1024) = K
//   vT: (1024, 8192) bf16 — row (h*64+c), col (b*1024+s)
// Per 64-key tile: K (4KB) + V^T (8KB) staged via global_load_lds (coalesced,
// 3 calls/wave), m97 2-barrier loop; Q (8KB) staged once. All MFMA fragments
// read from LDS (b128). P: wave-local pitch-68 LDS roundtrip (C->A layout).
// Softmax: r6's exact-t_max form (no online rescale, no per-tile shuffles).
// Mask arithmetic exact fp32 (__fadd_rn/__fmul_rn) as in rounds 2-6.
// ---------------------------------------------------------------------------
__global__ __launch_bounds__(256, 4) void attn_mfma(const ushort* __restrict__ qc,
                                                    const ushort* __restrict__ vT,
                                                    const float* __restrict__ mask,
                                                    const float* __restrict__ mkmin,
                                                    ushort* __restrict__ z)
{
    __shared__ ushort Qs[128 * 32];      // 8 KB   row = q-local, 32 elems
    __shared__ ushort Ks[64 * 32];       // 4 KB   row = key-local, 32 elems
    __shared__ ushort Vts[64 * 64];      // 8 KB   row = vcol-local, 64 keys
    __shared__ ushort Ps[4][32][68];     // 17.4 KB per-wave P

    const int tid  = threadIdx.x;
    const int wave = tid >> 6;
    const int lane = tid & 63;
    const int ln   = lane & 15;
    const int hi   = lane >> 4;
    const int qt = blockIdx.x, h = blockIdx.y, b = blockIdx.z;
    const int s0q = qt << 7;

    // ---- stage Q once: 2 coalesced gl2lds16 calls per wave (16 rows each)
    #pragma unroll
    for (int c = 0; c < 2; ++c) {
        const int cc = wave * 2 + c;
        const ushort* g = qc + (size_t)(b * 1024 + s0q + cc * 16 + (lane >> 2)) * 1024
                          + h * 32 + (lane & 3) * 8;
        gl2lds16(g, &Qs[cc * 512]);
    }

    const float mk_min = mkmin[b];
    float mqv[2][4], t_max[2][4];
    #pragma unroll
    for (int g = 0; g < 2; ++g)
        #pragma unroll
        for (int r = 0; r < 4; ++r) {
            mqv[g][r] = mask[b * 1024 + s0q + wave * 32 + g * 16 + hi * 4 + r];
            t_max[g][r] = __fmul_rn(fminf(1.f, __fadd_rn(mqv[g][r], mk_min)), -1.0e9f);
        }

    f32x4 acc_o[2][4];
    #pragma unroll
    for (int g = 0; g < 2; ++g)
        #pragma unroll
        for (int jo = 0; jo < 4; ++jo)
            acc_o[g][jo] = (f32x4){0.f, 0.f, 0.f, 0.f};
    float l_run[2][4] = {};

    const float scale = 0.17677669529663687f;   // 1/sqrt(32)

    for (int kt = 0; kt < 16; ++kt) {
        const int s0k = kt << 6;

        __syncthreads();   // prior tile's Ks/Vts frag reads done
        // stage K tile: 1 call/wave (keys wave*16..+15)
        {
            const ushort* g = qc + (size_t)(b * 1024 + s0k + wave * 16 + (lane >> 2)) * 1024
                              + 512 + h * 32 + (lane & 3) * 8;
            gl2lds16(g, &Ks[wave * 512]);
        }
        // stage V^T tile: 2 calls/wave (8 vcols x 128B each)
        #pragma unroll
        for (int c = 0; c < 2; ++c) {
            const int cc = wave * 2 + c;
            const ushort* g = vT + (size_t)(h * 64 + cc * 8 + (lane >> 3)) * 8192
                              + b * 1024 + s0k + (lane & 7) * 8;
            gl2lds16(g, &Vts[cc * 512]);
        }
        __syncthreads();   // vmcnt drained by compiler before barrier

        // key-mask for this tile (one 64B line, L1-hot)
        float mkv[4];
        #pragma unroll
        for (int j = 0; j < 4; ++j) mkv[j] = mask[b * 1024 + s0k + j * 16 + ln];

        // K B-frags from LDS (shared by both q-groups)
        bf16x8 bk[4];
        #pragma unroll
        for (int j = 0; j < 4; ++j)
            bk[j] = *(const bf16x8*)&Ks[(j * 16 + ln) * 32 + hi * 8];

        // QK + softmax per q-group
        #pragma unroll
        for (int g = 0; g < 2; ++g) {
            const bf16x8 aq = *(const bf16x8*)&Qs[(wave * 32 + g * 16 + ln) * 32 + hi * 8];
            f32x4 accS[4];
            #pragma unroll
            for (int j = 0; j < 4; ++j)
                accS[j] = __builtin_amdgcn_mfma_f32_16x16x32_bf16(aq, bk[j], (f32x4){0.f, 0.f, 0.f, 0.f}, 0, 0, 0);
            #pragma unroll
            for (int r = 0; r < 4; ++r) {
                #pragma unroll
                for (int j = 0; j < 4; ++j) {
                    const float m2 = fminf(1.f, __fadd_rn(mqv[g][r], mkv[j]));
                    const float t  = __fmul_rn(m2, -1.0e9f);
                    const float v  = __fadd_rn(__fmul_rn(accS[j][r], scale), t);
                    const float p  = __expf(v - t_max[g][r]);
                    l_run[g][r] += p;
                    Ps[wave][g * 16 + hi * 4 + r][j * 16 + ln] = f2bf(p);
                }
            }
        }

        // V B-frags from LDS (shared by both q-groups)
        bf16x8 bv0[4], bv1[4];
        #pragma unroll
        for (int jo = 0; jo < 4; ++jo) {
            bv0[jo] = *(const bf16x8*)&Vts[(jo * 16 + ln) * 64 + hi * 8];
            bv1[jo] = *(const bf16x8*)&Vts[(jo * 16 + ln) * 64 + 32 + hi * 8];
        }

        // PV (P read back as A-frags; wave-local DS ordering via lgkmcnt)
        #pragma unroll
        for (int g = 0; g < 2; ++g) {
            const bf16x8 pa0 = lds_ld8(&Ps[wave][g * 16 + ln][hi * 8]);
            const bf16x8 pa1 = lds_ld8(&Ps[wave][g * 16 + ln][32 + hi * 8]);
            #pragma unroll
            for (int jo = 0; jo < 4; ++jo) {
                acc_o[g][jo] = __builtin_amdgcn_mfma_f32_16x16x32_bf16(pa0, bv0[jo], acc_o[g][jo], 0, 0, 0);
                acc_o[g][jo] = __builtin_amdgcn_mfma_f32_16x16x32_bf16(pa1, bv1[jo], acc_o[g][jo], 0, 0, 0);
            }
        }
    }

    // final l reduction across the 16 lanes of each row (once per kernel)
    #pragma unroll
    for (int g = 0; g < 2; ++g)
        #pragma unroll
        for (int r = 0; r < 4; ++r) {
            #pragma unroll
            for (int off = 8; off >= 1; off >>= 1)
                l_run[g][r] += __shfl_xor(l_run[g][r], off);
        }

    #pragma unroll
    for (int g = 0; g < 2; ++g) {
        float invl[4];
        #pragma unroll
        for (int r = 0; r < 4; ++r) invl[r] = 1.f / l_run[g][r];
        #pragma unroll
        for (int jo = 0; jo < 4; ++jo)
            #pragma unroll
            for (int r = 0; r < 4; ++r)
                z[(size_t)(b * 1024 + s0q + wave * 32 + g * 16 + hi * 4 + r) * 1024 + h * 64 + jo * 16 + ln]
                    = f2bf(acc_o[g][jo][r] * invl[r]);
    }
}

// ---------------------------------------------------------------------------
extern "C" void kernel_launch(void* const* d_in, const int* in_sizes, int n_in,
                              void* d_out, int out_size, void* d_ws, size_t ws_size,
                              hipStream_t stream)
{
    const float* x     = (const float*)d_in[0];
    const float* mask  = (const float*)d_in[1];
    const float* wq    = (const float*)d_in[2];
    const float* bq    = (const float*)d_in[3];
    const float* w_ckv = (const float*)d_in[4];
    const float* wuk   = (const float*)d_in[5];
    const float* wuv   = (const float*)d_in[6];
    const float* wo    = (const float*)d_in[7];
    const float* bo    = (const float*)d_in[8];
    float* out = (float*)d_out;

    char* ws = (char*)d_ws;
    ushort* x_bf   = (ushort*)(ws);                         // 16 MB
    ushort* qc     = (ushort*)(ws + (size_t)(16u << 20));   // 16 MB (q_latent|K)
    ushort* vT     = (ushort*)(ws + (size_t)(32u << 20));   // 16 MB (1024,8192)
    ushort* z      = (ushort*)(ws + (size_t)(48u << 20));   // 16 MB
    ushort* wq_bf  = (ushort*)(ws + (size_t)(64u << 20));   //  2 MB
    ushort* wuk_bf = (ushort*)(ws + (size_t)(66u << 20));   //  1 MB
    ushort* wuv_t  = (ushort*)(ws + (size_t)(67u << 20));   //  1 MB
    ushort* wo_t   = (ushort*)(ws + (size_t)(68u << 20));   //  2 MB
    ushort* wcat_t = (ushort*)(ws + (size_t)(70u << 20));   //  2 MB (1024,1024)
    float*  b_cat  = (float*) (ws + (size_t)(72u << 20));   //  4 KB
    float*  mkmin  = (float*) (ws + (size_t)(72u << 20) + 8192); // 32 B

    const dim3 blk(256);
    const int M = 8192;

    cast_bf16<<<dim3(8192), blk, 0, stream>>>(x,   x_bf,   8192 * 1024);
    cast_bf16<<<dim3(1024), blk, 0, stream>>>(wq,  wq_bf,  1024 * 1024);
    cast_bf16<<<dim3(512),  blk, 0, stream>>>(wuk, wuk_bf, 512 * 1024);
    // wcat rows 512..1023 = w_ckv^T
    transpose_cast<<<dim3(16, 32), blk, 0, stream>>>(w_ckv, wcat_t + (size_t)512 * 1024, 1024, 512);
    transpose_cast<<<dim3(32, 16), blk, 0, stream>>>(wuv,   wuv_t,  512,  1024);
    transpose_cast<<<dim3(32, 32), blk, 0, stream>>>(wo,    wo_t,   1024, 1024);
    bias_fold<<<dim3(4), blk, 0, stream>>>(bq, wuk, b_cat);
    mask_min<<<dim3(8), blk, 0, stream>>>(mask, mkmin);

    // wcat rows 0..511 = wqk[l][d] = sum_n wuk[l][n]*wq[d][n]
    gemm_bt<false, false><<<dim3(8, 4), blk, 0, stream>>>(wuk_bf, wq_bf, nullptr, wcat_t,
                                                          512, 1024, 1024, 1024, 1024, 1024);

    // qc = x @ wcat^T + b_cat     (8192, 1024, K=1024): [q_latent | combined]
    gemm_bt<false, true ><<<dim3(8, 64), blk, 0, stream>>>(x_bf, wcat_t, b_cat, qc,
                                                           M, 1024, 1024, 1024, 1024, 1024);

    // vT = wuv^T @ combined^T     (1024, 8192, K=512)
    gemm_bt<false, false><<<dim3(64, 8), blk, 0, stream>>>(wuv_t, qc + 512, nullptr, vT,
                                                           1024, M, 512, 512, 1024, 8192);

    attn_mfma<<<dim3(8, 16, 8), blk, 0, stream>>>(qc, vT, mask, mkmin, z);

    // out = z @ wo^T + bo         (8192, 1024, K=1024)
    gemm_bt<true,  true ><<<dim3(8, 64), blk, 0, stream>>>(z, wo_t, bo, out,
                                                           M, 1024, 1024, 1024, 1024, 1024);
}

// Round 8
// 313.535 us; speedup vs baseline: 1.3724x; 1.0192x over previous
//
#include <hip/hip_runtime.h>
#include <cmath>

typedef __attribute__((ext_vector_type(8))) short bf16x8;
typedef __attribute__((ext_vector_type(4))) short bf16x4;
typedef __attribute__((ext_vector_type(4))) float f32x4;

__device__ __forceinline__ float bf2f(ushort u) {
    union { unsigned int u; float f; } c;
    c.u = ((unsigned int)u) << 16;
    return c.f;
}
__device__ __forceinline__ ushort f2bf(float f) {
    union { float f; unsigned int u; } c;
    c.f = f;
    unsigned int lsb = (c.u >> 16) & 1u;
    return (ushort)((c.u + 0x7fffu + lsb) >> 16);
}

// 8-bf16 LDS load from an 8B-aligned address
__device__ __forceinline__ bf16x8 lds_ld8(const ushort* p) {
    const bf16x4 lo = *(const bf16x4*)p;
    const bf16x4 hi = *(const bf16x4*)(p + 4);
    bf16x8 r;
    r[0] = lo[0]; r[1] = lo[1]; r[2] = lo[2]; r[3] = lo[3];
    r[4] = hi[0]; r[5] = hi[1]; r[6] = hi[2]; r[7] = hi[3];
    return r;
}

// async global->LDS, 16B per lane. LDS dest = wave-uniform base + lane*16.
__device__ __forceinline__ void gl2lds16(const ushort* g, ushort* l) {
    __builtin_amdgcn_global_load_lds((const __attribute__((address_space(1))) void*)g,
                                     (__attribute__((address_space(3))) void*)l,
                                     16, 0, 0);
}

// ---------------------------------------------------------------------------
__global__ __launch_bounds__(256) void cast_bf16(const float* __restrict__ in,
                                                 ushort* __restrict__ out, int n)
{
    int i = (blockIdx.x * 256 + threadIdx.x) * 4;
    if (i < n) {
        const float4 v = *(const float4*)(in + i);
        ushort4 o;
        o.x = f2bf(v.x); o.y = f2bf(v.y); o.z = f2bf(v.z); o.w = f2bf(v.w);
        *(ushort4*)(out + i) = o;
    }
}

// transpose + cast: in (R,C) fp32 row-major -> out (C,R) bf16 row-major
__global__ __launch_bounds__(256) void transpose_cast(const float* __restrict__ in,
                                                      ushort* __restrict__ out,
                                                      int R, int C)
{
    __shared__ float t[32][33];
    const int tx = threadIdx.x & 31;
    const int ty = threadIdx.x >> 5;
    const int r0 = blockIdx.y << 5;
    const int c0 = blockIdx.x << 5;
    #pragma unroll
    for (int i = ty; i < 32; i += 8)
        t[i][tx] = in[(size_t)(r0 + i) * C + c0 + tx];
    __syncthreads();
    #pragma unroll
    for (int i = ty; i < 32; i += 8)
        out[(size_t)(c0 + i) * R + r0 + tx] = f2bf(t[tx][i]);
}

// b_cat[n] = sum_o bq[o]*wuk[n][o] for n<512, else 0   (fp32, n in 0..1023)
__global__ __launch_bounds__(256) void bias_fold(const float* __restrict__ bq,
                                                 const float* __restrict__ wuk,
                                                 float* __restrict__ b_cat)
{
    const int n = blockIdx.x * 256 + threadIdx.x;
    float s = 0.f;
    if (n < 512) {
        for (int o = 0; o < 1024; o += 4) {
            const float4 w = *(const float4*)(wuk + (size_t)n * 1024 + o);
            const float4 q = *(const float4*)(bq + o);
            s = fmaf(q.x, w.x, s); s = fmaf(q.y, w.y, s);
            s = fmaf(q.z, w.z, s); s = fmaf(q.w, w.w, s);
        }
    }
    b_cat[n] = s;
}

// mkmin[b] = min_s mask[b, s]   (one block per batch)
__global__ __launch_bounds__(256) void mask_min(const float* __restrict__ mask,
                                                float* __restrict__ mkmin)
{
    __shared__ float red[4];
    const int b = blockIdx.x;
    const int tid = threadIdx.x;
    const float4 v = *(const float4*)(mask + b * 1024 + tid * 4);
    float m = fminf(fminf(v.x, v.y), fminf(v.z, v.w));
    #pragma unroll
    for (int off = 32; off >= 1; off >>= 1)
        m = fminf(m, __shfl_xor(m, off));
    if ((tid & 63) == 0) red[tid >> 6] = m;
    __syncthreads();
    if (tid == 0)
        mkmin[b] = fminf(fminf(red[0], red[1]), fminf(red[2], red[3]));
}

// ---------------------------------------------------------------------------
// bf16 MFMA GEMM: C[M,N] = A[M,K] @ Bt[N,K]^T (+bias), strided rows.
// 128x128x32 tile, 256 threads = 4 waves (2x2), each wave 4x4 of 16x16x32.
// Double-buffered LDS: stage(k+1) issued AFTER the barrier, in flight during
// compute(k) — each barrier drains a load issued a full compute-phase ago.
// Requires K % 64 == 0 (all call sites: 1024, 512).
// ---------------------------------------------------------------------------
template<bool OUT_F32, bool HAS_BIAS>
__global__ __launch_bounds__(256) void gemm_bt(const ushort* __restrict__ A,
                                               const ushort* __restrict__ Bt,
                                               const float* __restrict__ bias,
                                               void* __restrict__ Cv,
                                               int M, int N, int K,
                                               int lda, int ldb, int ldc)
{
    __shared__ ushort As[2][128 * 32];
    __shared__ ushort Bs[2][128 * 32];

    const int tid  = threadIdx.x;
    const int wave = tid >> 6;
    const int lane = tid & 63;
    const int row0 = blockIdx.y << 7;
    const int col0 = blockIdx.x << 7;

    const int srow = lane >> 2;
    const int skc  = (lane & 3) << 3;
    const ushort* Ag0 = A  + (size_t)(row0 + wave * 32 +      srow) * lda + skc;
    const ushort* Ag1 = A  + (size_t)(row0 + wave * 32 + 16 + srow) * lda + skc;
    const ushort* Bg0 = Bt + (size_t)(col0 + wave * 32 +      srow) * ldb + skc;
    const ushort* Bg1 = Bt + (size_t)(col0 + wave * 32 + 16 + srow) * ldb + skc;

    const int wr = (wave >> 1) << 6;
    const int wc = (wave & 1) << 6;
    const int ln = lane & 15;
    const int hi = lane >> 4;
    const int a_off = (wr + ln) * 32 + hi * 8;
    const int b_off = (wc + ln) * 32 + hi * 8;

    f32x4 acc[4][4];
    #pragma unroll
    for (int i = 0; i < 4; ++i)
        #pragma unroll
        for (int j = 0; j < 4; ++j)
            acc[i][j] = (f32x4){0.f, 0.f, 0.f, 0.f};

    // prologue: stage k=0 into buffer 0
    gl2lds16(Ag0, &As[0][(wave * 2 + 0) * 512]);
    gl2lds16(Ag1, &As[0][(wave * 2 + 1) * 512]);
    gl2lds16(Bg0, &Bs[0][(wave * 2 + 0) * 512]);
    gl2lds16(Bg1, &Bs[0][(wave * 2 + 1) * 512]);

    for (int k0 = 0; k0 < K; k0 += 64) {
        // ---- sub-step A: compute buf0 (k0), prefetch k0+32 into buf1
        __syncthreads();          // stage(k0) landed; prior reads of buf1 done
        {
            const int kn = k0 + 32;   // kn < K since K % 64 == 0
            gl2lds16(Ag0 + kn, &As[1][(wave * 2 + 0) * 512]);
            gl2lds16(Ag1 + kn, &As[1][(wave * 2 + 1) * 512]);
            gl2lds16(Bg0 + kn, &Bs[1][(wave * 2 + 0) * 512]);
            gl2lds16(Bg1 + kn, &Bs[1][(wave * 2 + 1) * 512]);
        }
        {
            bf16x8 a[4], b[4];
            #pragma unroll
            for (int i = 0; i < 4; ++i) a[i] = *(const bf16x8*)&As[0][a_off + i * 512];
            #pragma unroll
            for (int j = 0; j < 4; ++j) b[j] = *(const bf16x8*)&Bs[0][b_off + j * 512];
            #pragma unroll
            for (int i = 0; i < 4; ++i)
                #pragma unroll
                for (int j = 0; j < 4; ++j)
                    acc[i][j] = __builtin_amdgcn_mfma_f32_16x16x32_bf16(a[i], b[j], acc[i][j], 0, 0, 0);
        }
        // ---- sub-step B: compute buf1 (k0+32), prefetch k0+64 into buf0
        __syncthreads();          // stage(k0+32) landed; buf0 reads done
        if (k0 + 64 < K) {
            const int kn = k0 + 64;
            gl2lds16(Ag0 + kn, &As[0][(wave * 2 + 0) * 512]);
            gl2lds16(Ag1 + kn, &As[0][(wave * 2 + 1) * 512]);
            gl2lds16(Bg0 + kn, &Bs[0][(wave * 2 + 0) * 512]);
            gl2lds16(Bg1 + kn, &Bs[0][(wave * 2 + 1) * 512]);
        }
        {
            bf16x8 a[4], b[4];
            #pragma unroll
            for (int i = 0; i < 4; ++i) a[i] = *(const bf16x8*)&As[1][a_off + i * 512];
            #pragma unroll
            for (int j = 0; j < 4; ++j) b[j] = *(const bf16x8*)&Bs[1][b_off + j * 512];
            #pragma unroll
            for (int i = 0; i < 4; ++i)
                #pragma unroll
                for (int j = 0; j < 4; ++j)
                    acc[i][j] = __builtin_amdgcn_mfma_f32_16x16x32_bf16(a[i], b[j], acc[i][j], 0, 0, 0);
        }
    }

    #pragma unroll
    for (int j = 0; j < 4; ++j) {
        const int col = col0 + wc + (j << 4) + ln;
        const float bb = HAS_BIAS ? bias[col] : 0.f;
        #pragma unroll
        for (int i = 0; i < 4; ++i) {
            const int rbase = row0 + wr + (i << 4) + (hi << 2);
            #pragma unroll
            for (int r = 0; r < 4; ++r) {
                const float v = acc[i][j][r] + bb;
                if (OUT_F32) ((float*)Cv)[(size_t)(rbase + r) * ldc + col] = v;
                else         ((ushort*)Cv)[(size_t)(rbase + r) * ldc + col] = f2bf(v);
            }
        }
    }
}

// ---------------------------------------------------------------------------
// MFMA flash attention, fragment-major LDS (conflict-free b128 reads).
// Block = (b, h, 128-query tile); 4 waves x 32 queries. Grid 1024 = 4 blk/CU.
//   qc: fused (8192, 1024) bf16 — cols [0,512) = q_latent, [512,1024) = K
//   vT: (1024, 8192) bf16 — row (h*64+c), col (b*1024+s)
// LDS tiles stored per-fragment: gl2lds16 writes base+lane*16 and the global
// source per lane is chosen as (row=ln, colblock=hi), so fragment reads are
// lane-linear b128 — zero bank conflicts. P: wave-local pitch-68 roundtrip.
// Softmax: exact-t_max form (no online rescale). Mask math exact fp32.
// ---------------------------------------------------------------------------
__global__ __launch_bounds__(256, 4) void attn_mfma(const ushort* __restrict__ qc,
                                                    const ushort* __restrict__ vT,
                                                    const float* __restrict__ mask,
                                                    const float* __restrict__ mkmin,
                                                    ushort* __restrict__ z)
{
    __shared__ ushort Qs[8 * 512];       // 8 KB  frag f = 16q-group (wave*2+g)
    __shared__ ushort Ks[4 * 512];       // 4 KB  frag j = 16-key group
    __shared__ ushort Vts[8 * 512];      // 8 KB  frag f = (jo,half)
    __shared__ ushort Ps[4][32][68];     // 17.4 KB per-wave P

    const int tid  = threadIdx.x;
    const int wave = tid >> 6;
    const int lane = tid & 63;
    const int ln   = lane & 15;
    const int hi   = lane >> 4;
    const int qt = blockIdx.x, h = blockIdx.y, b = blockIdx.z;
    const int s0q = qt << 7;

    // ---- stage Q once, fragment-major (frag f = wave*2+c)
    #pragma unroll
    for (int c = 0; c < 2; ++c) {
        const int f = wave * 2 + c;
        const ushort* g = qc + (size_t)(b * 1024 + s0q + f * 16 + ln) * 1024 + h * 32 + hi * 8;
        gl2lds16(g, &Qs[f * 512]);
    }

    const float mk_min = mkmin[b];
    float mqv[2][4], t_max[2][4];
    #pragma unroll
    for (int g = 0; g < 2; ++g)
        #pragma unroll
        for (int r = 0; r < 4; ++r) {
            mqv[g][r] = mask[b * 1024 + s0q + wave * 32 + g * 16 + hi * 4 + r];
            t_max[g][r] = __fmul_rn(fminf(1.f, __fadd_rn(mqv[g][r], mk_min)), -1.0e9f);
        }

    f32x4 acc_o[2][4];
    #pragma unroll
    for (int g = 0; g < 2; ++g)
        #pragma unroll
        for (int jo = 0; jo < 4; ++jo)
            acc_o[g][jo] = (f32x4){0.f, 0.f, 0.f, 0.f};
    float l_run[2][4] = {};

    const float scale = 0.17677669529663687f;   // 1/sqrt(32)

    for (int kt = 0; kt < 16; ++kt) {
        const int s0k = kt << 6;

        __syncthreads();   // prior tile's Ks/Vts frag reads done
        // stage K tile: frag = wave (16 keys x 32 dims)
        {
            const ushort* g = qc + (size_t)(b * 1024 + s0k + wave * 16 + ln) * 1024
                              + 512 + h * 32 + hi * 8;
            gl2lds16(g, &Ks[wave * 512]);
        }
        // stage V^T tile: frags f = wave*2+c, f = jo*2+half
        #pragma unroll
        for (int c = 0; c < 2; ++c) {
            const int f = wave * 2 + c;
            const ushort* g = vT + (size_t)(h * 64 + (f >> 1) * 16 + ln) * 8192
                              + b * 1024 + s0k + (f & 1) * 32 + hi * 8;
            gl2lds16(g, &Vts[f * 512]);
        }
        __syncthreads();   // staging landed

        // key-mask for this tile (one 64B line, L1-hot)
        float mkv[4];
        #pragma unroll
        for (int j = 0; j < 4; ++j) mkv[j] = mask[b * 1024 + s0k + j * 16 + ln];

        // K B-frags: lane-linear reads, conflict-free
        bf16x8 bk[4];
        #pragma unroll
        for (int j = 0; j < 4; ++j)
            bk[j] = *(const bf16x8*)&Ks[j * 512 + lane * 8];

        // QK + softmax per q-group
        #pragma unroll
        for (int g = 0; g < 2; ++g) {
            const bf16x8 aq = *(const bf16x8*)&Qs[(wave * 2 + g) * 512 + lane * 8];
            f32x4 accS[4];
            #pragma unroll
            for (int j = 0; j < 4; ++j)
                accS[j] = __builtin_amdgcn_mfma_f32_16x16x32_bf16(aq, bk[j], (f32x4){0.f, 0.f, 0.f, 0.f}, 0, 0, 0);
            #pragma unroll
            for (int r = 0; r < 4; ++r) {
                #pragma unroll
                for (int j = 0; j < 4; ++j) {
                    const float m2 = fminf(1.f, __fadd_rn(mqv[g][r], mkv[j]));
                    const float t  = __fmul_rn(m2, -1.0e9f);
                    const float v  = __fadd_rn(__fmul_rn(accS[j][r], scale), t);
                    const float p  = __expf(v - t_max[g][r]);
                    l_run[g][r] += p;
                    Ps[wave][g * 16 + hi * 4 + r][j * 16 + ln] = f2bf(p);
                }
            }
        }

        // V B-frags: lane-linear reads, conflict-free
        bf16x8 bv0[4], bv1[4];
        #pragma unroll
        for (int jo = 0; jo < 4; ++jo) {
            bv0[jo] = *(const bf16x8*)&Vts[(jo * 2 + 0) * 512 + lane * 8];
            bv1[jo] = *(const bf16x8*)&Vts[(jo * 2 + 1) * 512 + lane * 8];
        }

        // PV (P read back as A-frags; wave-local DS ordering via lgkmcnt)
        #pragma unroll
        for (int g = 0; g < 2; ++g) {
            const bf16x8 pa0 = lds_ld8(&Ps[wave][g * 16 + ln][hi * 8]);
            const bf16x8 pa1 = lds_ld8(&Ps[wave][g * 16 + ln][32 + hi * 8]);
            #pragma unroll
            for (int jo = 0; jo < 4; ++jo) {
                acc_o[g][jo] = __builtin_amdgcn_mfma_f32_16x16x32_bf16(pa0, bv0[jo], acc_o[g][jo], 0, 0, 0);
                acc_o[g][jo] = __builtin_amdgcn_mfma_f32_16x16x32_bf16(pa1, bv1[jo], acc_o[g][jo], 0, 0, 0);
            }
        }
    }

    // final l reduction across the 16 lanes of each row (once per kernel)
    #pragma unroll
    for (int g = 0; g < 2; ++g)
        #pragma unroll
        for (int r = 0; r < 4; ++r) {
            #pragma unroll
            for (int off = 8; off >= 1; off >>= 1)
                l_run[g][r] += __shfl_xor(l_run[g][r], off);
        }

    #pragma unroll
    for (int g = 0; g < 2; ++g) {
        float invl[4];
        #pragma unroll
        for (int r = 0; r < 4; ++r) invl[r] = 1.f / l_run[g][r];
        #pragma unroll
        for (int jo = 0; jo < 4; ++jo)
            #pragma unroll
            for (int r = 0; r < 4; ++r)
                z[(size_t)(b * 1024 + s0q + wave * 32 + g * 16 + hi * 4 + r) * 1024 + h * 64 + jo * 16 + ln]
                    = f2bf(acc_o[g][jo][r] * invl[r]);
    }
}

// ---------------------------------------------------------------------------
extern "C" void kernel_launch(void* const* d_in, const int* in_sizes, int n_in,
                              void* d_out, int out_size, void* d_ws, size_t ws_size,
                              hipStream_t stream)
{
    const float* x     = (const float*)d_in[0];
    const float* mask  = (const float*)d_in[1];
    const float* wq    = (const float*)d_in[2];
    const float* bq    = (const float*)d_in[3];
    const float* w_ckv = (const float*)d_in[4];
    const float* wuk   = (const float*)d_in[5];
    const float* wuv   = (const float*)d_in[6];
    const float* wo    = (const float*)d_in[7];
    const float* bo    = (const float*)d_in[8];
    float* out = (float*)d_out;

    char* ws = (char*)d_ws;
    ushort* x_bf   = (ushort*)(ws);                         // 16 MB
    ushort* qc     = (ushort*)(ws + (size_t)(16u << 20));   // 16 MB (q_latent|K)
    ushort* vT     = (ushort*)(ws + (size_t)(32u << 20));   // 16 MB (1024,8192)
    ushort* z      = (ushort*)(ws + (size_t)(48u << 20));   // 16 MB
    ushort* wq_bf  = (ushort*)(ws + (size_t)(64u << 20));   //  2 MB
    ushort* wuk_bf = (ushort*)(ws + (size_t)(66u << 20));   //  1 MB
    ushort* wuv_t  = (ushort*)(ws + (size_t)(67u << 20));   //  1 MB
    ushort* wo_t   = (ushort*)(ws + (size_t)(68u << 20));   //  2 MB
    ushort* wcat_t = (ushort*)(ws + (size_t)(70u << 20));   //  2 MB (1024,1024)
    float*  b_cat  = (float*) (ws + (size_t)(72u << 20));   //  4 KB
    float*  mkmin  = (float*) (ws + (size_t)(72u << 20) + 8192); // 32 B

    const dim3 blk(256);
    const int M = 8192;

    cast_bf16<<<dim3(8192), blk, 0, stream>>>(x,   x_bf,   8192 * 1024);
    cast_bf16<<<dim3(1024), blk, 0, stream>>>(wq,  wq_bf,  1024 * 1024);
    cast_bf16<<<dim3(512),  blk, 0, stream>>>(wuk, wuk_bf, 512 * 1024);
    // wcat rows 512..1023 = w_ckv^T
    transpose_cast<<<dim3(16, 32), blk, 0, stream>>>(w_ckv, wcat_t + (size_t)512 * 1024, 1024, 512);
    transpose_cast<<<dim3(32, 16), blk, 0, stream>>>(wuv,   wuv_t,  512,  1024);
    transpose_cast<<<dim3(32, 32), blk, 0, stream>>>(wo,    wo_t,   1024, 1024);
    bias_fold<<<dim3(4), blk, 0, stream>>>(bq, wuk, b_cat);
    mask_min<<<dim3(8), blk, 0, stream>>>(mask, mkmin);

    // wcat rows 0..511 = wqk[l][d] = sum_n wuk[l][n]*wq[d][n]
    gemm_bt<false, false><<<dim3(8, 4), blk, 0, stream>>>(wuk_bf, wq_bf, nullptr, wcat_t,
                                                          512, 1024, 1024, 1024, 1024, 1024);

    // qc = x @ wcat^T + b_cat     (8192, 1024, K=1024): [q_latent | combined]
    gemm_bt<false, true ><<<dim3(8, 64), blk, 0, stream>>>(x_bf, wcat_t, b_cat, qc,
                                                           M, 1024, 1024, 1024, 1024, 1024);

    // vT = wuv^T @ combined^T     (1024, 8192, K=512)
    gemm_bt<false, false><<<dim3(64, 8), blk, 0, stream>>>(wuv_t, qc + 512, nullptr, vT,
                                                           1024, M, 512, 512, 1024, 8192);

    attn_mfma<<<dim3(8, 16, 8), blk, 0, stream>>>(qc, vT, mask, mkmin, z);

    // out = z @ wo^T + bo         (8192, 1024, K=1024)
    gemm_bt<true,  true ><<<dim3(8, 64), blk, 0, stream>>>(z, wo_t, bo, out,
                                                           M, 1024, 1024, 1024, 1024, 1024);
}

// Round 9
// 291.694 us; speedup vs baseline: 1.4752x; 1.0749x over previous
//
#include <hip/hip_runtime.h>
#include <cmath>

typedef __attribute__((ext_vector_type(8))) short bf16x8;
typedef __attribute__((ext_vector_type(4))) short bf16x4;
typedef __attribute__((ext_vector_type(4))) float f32x4;

__device__ __forceinline__ float bf2f(ushort u) {
    union { unsigned int u; float f; } c;
    c.u = ((unsigned int)u) << 16;
    return c.f;
}
__device__ __forceinline__ ushort f2bf(float f) {
    union { float f; unsigned int u; } c;
    c.f = f;
    unsigned int lsb = (c.u >> 16) & 1u;
    return (ushort)((c.u + 0x7fffu + lsb) >> 16);
}

// 8-bf16 LDS load from an 8B-aligned address
__device__ __forceinline__ bf16x8 lds_ld8(const ushort* p) {
    const bf16x4 lo = *(const bf16x4*)p;
    const bf16x4 hi = *(const bf16x4*)(p + 4);
    bf16x8 r;
    r[0] = lo[0]; r[1] = lo[1]; r[2] = lo[2]; r[3] = lo[3];
    r[4] = hi[0]; r[5] = hi[1]; r[6] = hi[2]; r[7] = hi[3];
    return r;
}

// async global->LDS, 16B per lane. LDS dest = wave-uniform base + lane*16.
__device__ __forceinline__ void gl2lds16(const ushort* g, ushort* l) {
    __builtin_amdgcn_global_load_lds((const __attribute__((address_space(1))) void*)g,
                                     (__attribute__((address_space(3))) void*)l,
                                     16, 0, 0);
}

// ---------------------------------------------------------------------------
// prep: fused prologue. blockIdx ranges:
//   [0,8192)        x cast (8192*1024 elems)
//   [8192,9216)     wq cast (1024*1024)
//   [9216,9728)     wuk cast (512*1024)
//   [9728,10240)    w_ckv transpose (16x32)  -> wcat_t rows 512..1023
//   [10240,10752)   wuv transpose (32x16)
//   [10752,11776)   wo transpose (32x32)
//   [11776,11780)   bias_fold
//   [11780,11788)   mask_min
// ---------------------------------------------------------------------------
__device__ __forceinline__ void cast_seg(const float* in, ushort* out, int bid)
{
    const int i = (bid * 256 + (int)threadIdx.x) * 4;
    const float4 v = *(const float4*)(in + i);
    ushort4 o;
    o.x = f2bf(v.x); o.y = f2bf(v.y); o.z = f2bf(v.z); o.w = f2bf(v.w);
    *(ushort4*)(out + i) = o;
}

__device__ __forceinline__ void transpose_seg(const float* in, ushort* out,
                                              int R, int C, int bx, int by,
                                              float (*t)[33])
{
    const int tx = threadIdx.x & 31;
    const int ty = threadIdx.x >> 5;
    const int r0 = by << 5;
    const int c0 = bx << 5;
    #pragma unroll
    for (int i = ty; i < 32; i += 8)
        t[i][tx] = in[(size_t)(r0 + i) * C + c0 + tx];
    __syncthreads();
    #pragma unroll
    for (int i = ty; i < 32; i += 8)
        out[(size_t)(c0 + i) * R + r0 + tx] = f2bf(t[tx][i]);
}

__global__ __launch_bounds__(256) void prep(const float* __restrict__ x,
                                            const float* __restrict__ wq,
                                            const float* __restrict__ wuk,
                                            const float* __restrict__ w_ckv,
                                            const float* __restrict__ wuv,
                                            const float* __restrict__ wo,
                                            const float* __restrict__ bq,
                                            const float* __restrict__ mask,
                                            ushort* __restrict__ x_bf,
                                            ushort* __restrict__ wq_bf,
                                            ushort* __restrict__ wuk_bf,
                                            ushort* __restrict__ wcat_t,
                                            ushort* __restrict__ wuv_t,
                                            ushort* __restrict__ wo_t,
                                            float* __restrict__ b_cat,
                                            float* __restrict__ mkmin)
{
    __shared__ float t[32][33];
    __shared__ float red[4];
    const int bid = blockIdx.x;
    const int tid = threadIdx.x;

    if (bid < 8192) {
        cast_seg(x, x_bf, bid);
    } else if (bid < 9216) {
        cast_seg(wq, wq_bf, bid - 8192);
    } else if (bid < 9728) {
        cast_seg(wuk, wuk_bf, bid - 9216);
    } else if (bid < 10240) {
        const int l = bid - 9728;
        transpose_seg(w_ckv, wcat_t + (size_t)512 * 1024, 1024, 512, l & 15, l >> 4, t);
    } else if (bid < 10752) {
        const int l = bid - 10240;
        transpose_seg(wuv, wuv_t, 512, 1024, l & 31, l >> 5, t);
    } else if (bid < 11776) {
        const int l = bid - 10752;
        transpose_seg(wo, wo_t, 1024, 1024, l & 31, l >> 5, t);
    } else if (bid < 11780) {
        const int n = (bid - 11776) * 256 + tid;
        float s = 0.f;
        if (n < 512) {
            for (int o = 0; o < 1024; o += 4) {
                const float4 w = *(const float4*)(wuk + (size_t)n * 1024 + o);
                const float4 q = *(const float4*)(bq + o);
                s = fmaf(q.x, w.x, s); s = fmaf(q.y, w.y, s);
                s = fmaf(q.z, w.z, s); s = fmaf(q.w, w.w, s);
            }
        }
        b_cat[n] = s;
    } else {
        const int b = bid - 11780;
        const float4 v = *(const float4*)(mask + b * 1024 + tid * 4);
        float m = fminf(fminf(v.x, v.y), fminf(v.z, v.w));
        #pragma unroll
        for (int off = 32; off >= 1; off >>= 1)
            m = fminf(m, __shfl_xor(m, off));
        if ((tid & 63) == 0) red[tid >> 6] = m;
        __syncthreads();
        if (tid == 0)
            mkmin[b] = fminf(fminf(red[0], red[1]), fminf(red[2], red[3]));
    }
}

// ---------------------------------------------------------------------------
// bf16 MFMA GEMM: C[M,N] = A[M,K] @ Bt[N,K]^T (+bias), strided rows.
// 128x64 tile, 256 threads = 4 waves (2x2), each wave 64x32 (4x2 of 16x16x32).
// Grid = (N/64, M/128) — 2x the blocks of the 128x128 tile for occupancy.
// Double-buffered LDS, stage(k+1) issued after the barrier. K % 64 == 0.
// ---------------------------------------------------------------------------
template<bool OUT_F32, bool HAS_BIAS>
__global__ __launch_bounds__(256) void gemm_bt(const ushort* __restrict__ A,
                                               const ushort* __restrict__ Bt,
                                               const float* __restrict__ bias,
                                               void* __restrict__ Cv,
                                               int M, int N, int K,
                                               int lda, int ldb, int ldc)
{
    __shared__ ushort As[2][128 * 32];   // 8 KB per buf
    __shared__ ushort Bs[2][64 * 32];    // 4 KB per buf

    const int tid  = threadIdx.x;
    const int wave = tid >> 6;
    const int lane = tid & 63;
    const int row0 = blockIdx.y << 7;
    const int col0 = blockIdx.x << 6;

    const int srow = lane >> 2;
    const int skc  = (lane & 3) << 3;
    const ushort* Ag0 = A  + (size_t)(row0 + wave * 32 +      srow) * lda + skc;
    const ushort* Ag1 = A  + (size_t)(row0 + wave * 32 + 16 + srow) * lda + skc;
    const ushort* Bg  = Bt + (size_t)(col0 + wave * 16 +      srow) * ldb + skc;

    const int wr = (wave >> 1) << 6;
    const int wc = (wave & 1) << 5;
    const int ln = lane & 15;
    const int hi = lane >> 4;
    const int a_off = (wr + ln) * 32 + hi * 8;
    const int b_off = (wc + ln) * 32 + hi * 8;

    f32x4 acc[4][2];
    #pragma unroll
    for (int i = 0; i < 4; ++i)
        #pragma unroll
        for (int j = 0; j < 2; ++j)
            acc[i][j] = (f32x4){0.f, 0.f, 0.f, 0.f};

    // prologue: stage k=0 into buffer 0
    gl2lds16(Ag0, &As[0][(wave * 2 + 0) * 512]);
    gl2lds16(Ag1, &As[0][(wave * 2 + 1) * 512]);
    gl2lds16(Bg,  &Bs[0][wave * 512]);

    for (int k0 = 0; k0 < K; k0 += 64) {
        // ---- sub-step A: compute buf0 (k0), prefetch k0+32 into buf1
        __syncthreads();
        {
            const int kn = k0 + 32;   // < K since K % 64 == 0
            gl2lds16(Ag0 + kn, &As[1][(wave * 2 + 0) * 512]);
            gl2lds16(Ag1 + kn, &As[1][(wave * 2 + 1) * 512]);
            gl2lds16(Bg  + kn, &Bs[1][wave * 512]);
        }
        {
            bf16x8 a[4], b[2];
            #pragma unroll
            for (int i = 0; i < 4; ++i) a[i] = *(const bf16x8*)&As[0][a_off + i * 512];
            #pragma unroll
            for (int j = 0; j < 2; ++j) b[j] = *(const bf16x8*)&Bs[0][b_off + j * 512];
            #pragma unroll
            for (int i = 0; i < 4; ++i)
                #pragma unroll
                for (int j = 0; j < 2; ++j)
                    acc[i][j] = __builtin_amdgcn_mfma_f32_16x16x32_bf16(a[i], b[j], acc[i][j], 0, 0, 0);
        }
        // ---- sub-step B: compute buf1 (k0+32), prefetch k0+64 into buf0
        __syncthreads();
        if (k0 + 64 < K) {
            const int kn = k0 + 64;
            gl2lds16(Ag0 + kn, &As[0][(wave * 2 + 0) * 512]);
            gl2lds16(Ag1 + kn, &As[0][(wave * 2 + 1) * 512]);
            gl2lds16(Bg  + kn, &Bs[0][wave * 512]);
        }
        {
            bf16x8 a[4], b[2];
            #pragma unroll
            for (int i = 0; i < 4; ++i) a[i] = *(const bf16x8*)&As[1][a_off + i * 512];
            #pragma unroll
            for (int j = 0; j < 2; ++j) b[j] = *(const bf16x8*)&Bs[1][b_off + j * 512];
            #pragma unroll
            for (int i = 0; i < 4; ++i)
                #pragma unroll
                for (int j = 0; j < 2; ++j)
                    acc[i][j] = __builtin_amdgcn_mfma_f32_16x16x32_bf16(a[i], b[j], acc[i][j], 0, 0, 0);
        }
    }

    #pragma unroll
    for (int j = 0; j < 2; ++j) {
        const int col = col0 + wc + (j << 4) + ln;
        const float bb = HAS_BIAS ? bias[col] : 0.f;
        #pragma unroll
        for (int i = 0; i < 4; ++i) {
            const int rbase = row0 + wr + (i << 4) + (hi << 2);
            #pragma unroll
            for (int r = 0; r < 4; ++r) {
                const float v = acc[i][j][r] + bb;
                if (OUT_F32) ((float*)Cv)[(size_t)(rbase + r) * ldc + col] = v;
                else         ((ushort*)Cv)[(size_t)(rbase + r) * ldc + col] = f2bf(v);
            }
        }
    }
}

// ---------------------------------------------------------------------------
// MFMA flash attention, fragment-major LDS (conflict-free b128 reads).
// Block = (b, h, 128-query tile); 4 waves x 32 queries. Grid 1024 = 4 blk/CU.
//   qc: fused (8192, 1024) bf16 — cols [0,512) = q_latent, [512,1024) = K
//   vT: (1024, 8192) bf16 — row (h*64+c), col (b*1024+s)
// Softmax: exact-t_max form (no online rescale). Mask math exact fp32.
// ---------------------------------------------------------------------------
__global__ __launch_bounds__(256, 4) void attn_mfma(const ushort* __restrict__ qc,
                                                    const ushort* __restrict__ vT,
                                                    const float* __restrict__ mask,
                                                    const float* __restrict__ mkmin,
                                                    ushort* __restrict__ z)
{
    __shared__ ushort Qs[8 * 512];       // 8 KB  frag f = 16q-group (wave*2+g)
    __shared__ ushort Ks[4 * 512];       // 4 KB  frag j = 16-key group
    __shared__ ushort Vts[8 * 512];      // 8 KB  frag f = (jo,half)
    __shared__ ushort Ps[4][32][68];     // 17.4 KB per-wave P

    const int tid  = threadIdx.x;
    const int wave = tid >> 6;
    const int lane = tid & 63;
    const int ln   = lane & 15;
    const int hi   = lane >> 4;
    const int qt = blockIdx.x, h = blockIdx.y, b = blockIdx.z;
    const int s0q = qt << 7;

    // ---- stage Q once, fragment-major (frag f = wave*2+c)
    #pragma unroll
    for (int c = 0; c < 2; ++c) {
        const int f = wave * 2 + c;
        const ushort* g = qc + (size_t)(b * 1024 + s0q + f * 16 + ln) * 1024 + h * 32 + hi * 8;
        gl2lds16(g, &Qs[f * 512]);
    }

    const float mk_min = mkmin[b];
    float mqv[2][4], t_max[2][4];
    #pragma unroll
    for (int g = 0; g < 2; ++g)
        #pragma unroll
        for (int r = 0; r < 4; ++r) {
            mqv[g][r] = mask[b * 1024 + s0q + wave * 32 + g * 16 + hi * 4 + r];
            t_max[g][r] = __fmul_rn(fminf(1.f, __fadd_rn(mqv[g][r], mk_min)), -1.0e9f);
        }

    f32x4 acc_o[2][4];
    #pragma unroll
    for (int g = 0; g < 2; ++g)
        #pragma unroll
        for (int jo = 0; jo < 4; ++jo)
            acc_o[g][jo] = (f32x4){0.f, 0.f, 0.f, 0.f};
    float l_run[2][4] = {};

    const float scale = 0.17677669529663687f;   // 1/sqrt(32)

    for (int kt = 0; kt < 16; ++kt) {
        const int s0k = kt << 6;

        __syncthreads();   // prior tile's Ks/Vts frag reads done
        {
            const ushort* g = qc + (size_t)(b * 1024 + s0k + wave * 16 + ln) * 1024
                              + 512 + h * 32 + hi * 8;
            gl2lds16(g, &Ks[wave * 512]);
        }
        #pragma unroll
        for (int c = 0; c < 2; ++c) {
            const int f = wave * 2 + c;
            const ushort* g = vT + (size_t)(h * 64 + (f >> 1) * 16 + ln) * 8192
                              + b * 1024 + s0k + (f & 1) * 32 + hi * 8;
            gl2lds16(g, &Vts[f * 512]);
        }
        __syncthreads();   // staging landed

        float mkv[4];
        #pragma unroll
        for (int j = 0; j < 4; ++j) mkv[j] = mask[b * 1024 + s0k + j * 16 + ln];

        bf16x8 bk[4];
        #pragma unroll
        for (int j = 0; j < 4; ++j)
            bk[j] = *(const bf16x8*)&Ks[j * 512 + lane * 8];

        #pragma unroll
        for (int g = 0; g < 2; ++g) {
            const bf16x8 aq = *(const bf16x8*)&Qs[(wave * 2 + g) * 512 + lane * 8];
            f32x4 accS[4];
            #pragma unroll
            for (int j = 0; j < 4; ++j)
                accS[j] = __builtin_amdgcn_mfma_f32_16x16x32_bf16(aq, bk[j], (f32x4){0.f, 0.f, 0.f, 0.f}, 0, 0, 0);
            #pragma unroll
            for (int r = 0; r < 4; ++r) {
                #pragma unroll
                for (int j = 0; j < 4; ++j) {
                    const float m2 = fminf(1.f, __fadd_rn(mqv[g][r], mkv[j]));
                    const float t  = __fmul_rn(m2, -1.0e9f);
                    const float v  = __fadd_rn(__fmul_rn(accS[j][r], scale), t);
                    const float p  = __expf(v - t_max[g][r]);
                    l_run[g][r] += p;
                    Ps[wave][g * 16 + hi * 4 + r][j * 16 + ln] = f2bf(p);
                }
            }
        }

        bf16x8 bv0[4], bv1[4];
        #pragma unroll
        for (int jo = 0; jo < 4; ++jo) {
            bv0[jo] = *(const bf16x8*)&Vts[(jo * 2 + 0) * 512 + lane * 8];
            bv1[jo] = *(const bf16x8*)&Vts[(jo * 2 + 1) * 512 + lane * 8];
        }

        #pragma unroll
        for (int g = 0; g < 2; ++g) {
            const bf16x8 pa0 = lds_ld8(&Ps[wave][g * 16 + ln][hi * 8]);
            const bf16x8 pa1 = lds_ld8(&Ps[wave][g * 16 + ln][32 + hi * 8]);
            #pragma unroll
            for (int jo = 0; jo < 4; ++jo) {
                acc_o[g][jo] = __builtin_amdgcn_mfma_f32_16x16x32_bf16(pa0, bv0[jo], acc_o[g][jo], 0, 0, 0);
                acc_o[g][jo] = __builtin_amdgcn_mfma_f32_16x16x32_bf16(pa1, bv1[jo], acc_o[g][jo], 0, 0, 0);
            }
        }
    }

    #pragma unroll
    for (int g = 0; g < 2; ++g)
        #pragma unroll
        for (int r = 0; r < 4; ++r) {
            #pragma unroll
            for (int off = 8; off >= 1; off >>= 1)
                l_run[g][r] += __shfl_xor(l_run[g][r], off);
        }

    #pragma unroll
    for (int g = 0; g < 2; ++g) {
        float invl[4];
        #pragma unroll
        for (int r = 0; r < 4; ++r) invl[r] = 1.f / l_run[g][r];
        #pragma unroll
        for (int jo = 0; jo < 4; ++jo)
            #pragma unroll
            for (int r = 0; r < 4; ++r)
                z[(size_t)(b * 1024 + s0q + wave * 32 + g * 16 + hi * 4 + r) * 1024 + h * 64 + jo * 16 + ln]
                    = f2bf(acc_o[g][jo][r] * invl[r]);
    }
}

// ---------------------------------------------------------------------------
extern "C" void kernel_launch(void* const* d_in, const int* in_sizes, int n_in,
                              void* d_out, int out_size, void* d_ws, size_t ws_size,
                              hipStream_t stream)
{
    const float* x     = (const float*)d_in[0];
    const float* mask  = (const float*)d_in[1];
    const float* wq    = (const float*)d_in[2];
    const float* bq    = (const float*)d_in[3];
    const float* w_ckv = (const float*)d_in[4];
    const float* wuk   = (const float*)d_in[5];
    const float* wuv   = (const float*)d_in[6];
    const float* wo    = (const float*)d_in[7];
    const float* bo    = (const float*)d_in[8];
    float* out = (float*)d_out;

    char* ws = (char*)d_ws;
    ushort* x_bf   = (ushort*)(ws);                         // 16 MB
    ushort* qc     = (ushort*)(ws + (size_t)(16u << 20));   // 16 MB (q_latent|K)
    ushort* vT     = (ushort*)(ws + (size_t)(32u << 20));   // 16 MB (1024,8192)
    ushort* z      = (ushort*)(ws + (size_t)(48u << 20));   // 16 MB
    ushort* wq_bf  = (ushort*)(ws + (size_t)(64u << 20));   //  2 MB
    ushort* wuk_bf = (ushort*)(ws + (size_t)(66u << 20));   //  1 MB
    ushort* wuv_t  = (ushort*)(ws + (size_t)(67u << 20));   //  1 MB
    ushort* wo_t   = (ushort*)(ws + (size_t)(68u << 20));   //  2 MB
    ushort* wcat_t = (ushort*)(ws + (size_t)(70u << 20));   //  2 MB (1024,1024)
    float*  b_cat  = (float*) (ws + (size_t)(72u << 20));   //  4 KB
    float*  mkmin  = (float*) (ws + (size_t)(72u << 20) + 8192); // 32 B

    const dim3 blk(256);
    const int M = 8192;

    // fused prologue: casts, transposes, bias_fold, mask_min (one launch)
    prep<<<dim3(11788), blk, 0, stream>>>(x, wq, wuk, w_ckv, wuv, wo, bq, mask,
                                          x_bf, wq_bf, wuk_bf, wcat_t, wuv_t, wo_t,
                                          b_cat, mkmin);

    // wcat rows 0..511 = wqk[l][d] = sum_n wuk[l][n]*wq[d][n]
    gemm_bt<false, false><<<dim3(16, 4), blk, 0, stream>>>(wuk_bf, wq_bf, nullptr, wcat_t,
                                                           512, 1024, 1024, 1024, 1024, 1024);

    // qc = x @ wcat^T + b_cat     (8192, 1024, K=1024): [q_latent | combined]
    gemm_bt<false, true ><<<dim3(16, 64), blk, 0, stream>>>(x_bf, wcat_t, b_cat, qc,
                                                            M, 1024, 1024, 1024, 1024, 1024);

    // vT = wuv^T @ combined^T     (1024, 8192, K=512)
    gemm_bt<false, false><<<dim3(128, 8), blk, 0, stream>>>(wuv_t, qc + 512, nullptr, vT,
                                                            1024, M, 512, 512, 1024, 8192);

    attn_mfma<<<dim3(8, 16, 8), blk, 0, stream>>>(qc, vT, mask, mkmin, z);

    // out = z @ wo^T + bo         (8192, 1024, K=1024)
    gemm_bt<true,  true ><<<dim3(16, 64), blk, 0, stream>>>(z, wo_t, bo, out,
                                                            M, 1024, 1024, 1024, 1024, 1024);
}